// Round 3
// baseline (782.018 us; speedup 1.0000x reference)
//
#include <hip/hip_runtime.h>
#include <hip/hip_bf16.h>

// Problem constants (B=16, N=S=2048, D=256, fp32 in/out).
#define BB 16
#define NN 2048
#define SS 2048
#define DD 256
#define EE (BB * NN * DD)  // 8388608 elements per tensor
#define STASH_BYTES ((size_t)3 * (size_t)EE * 2)  // Qh|Ql|Kh fp16 = 50.3 MB

typedef _Float16 f16x8 __attribute__((ext_vector_type(8)));
typedef _Float16 f16x4 __attribute__((ext_vector_type(4)));
typedef float floatx4 __attribute__((ext_vector_type(4)));
typedef short s16x8 __attribute__((ext_vector_type(8)));

__device__ __forceinline__ void async16(const _Float16* g, _Float16* l) {
    __builtin_amdgcn_global_load_lds((__attribute__((address_space(1))) void*)g,
                                     (__attribute__((address_space(3))) void*)l, 16, 0, 0);
}

__device__ __forceinline__ void nt_store4(float* p, float x, float y, float z, float w) {
    floatx4 v = {x, y, z, w};
    __builtin_nontemporal_store(v, (floatx4*)p);
}

// ---------------------------------------------------------------------------
// Kernel 0: fp16 split. Q -> (Qh, Ql) with q = qh + ql exact to ~2^-22;
// K -> Kh only. stash: Qh[EE] | Ql[EE] | Kh[EE] fp16 (50 MB). Fused path
// puts the stash in d_ws (A region would race with phase-2 A writes);
// fallback path puts it in the A-output region as before.
// ---------------------------------------------------------------------------
__global__ __launch_bounds__(256) void k_convert(const float* __restrict__ Q,
                                                 const float* __restrict__ K,
                                                 _Float16* __restrict__ stash) {
    size_t idx = ((size_t)blockIdx.x * 256 + threadIdx.x) * 4;  // over 2*EE elems
    if (idx < (size_t)EE) {
        float4 v = *(const float4*)(Q + idx);
        f16x4 h, l;
        h.x = (_Float16)v.x; h.y = (_Float16)v.y; h.z = (_Float16)v.z; h.w = (_Float16)v.w;
        l.x = (_Float16)(v.x - (float)h.x);
        l.y = (_Float16)(v.y - (float)h.y);
        l.z = (_Float16)(v.z - (float)h.z);
        l.w = (_Float16)(v.w - (float)h.w);
        *(f16x4*)(stash + idx) = h;
        *(f16x4*)(stash + (size_t)EE + idx) = l;
    } else {
        size_t off = idx - (size_t)EE;
        float4 v = *(const float4*)(K + off);
        f16x4 h;
        h.x = (_Float16)v.x; h.y = (_Float16)v.y; h.z = (_Float16)v.z; h.w = (_Float16)v.w;
        *(f16x4*)(stash + 2 * (size_t)EE + off) = h;
    }
}

// ---------------------------------------------------------------------------
// Shared per-row sparsemax + sparse PV (proven R2 logic, verbatim).
// Reads the int16 Q7.8 score half-slot of `row`, expands to fp32 gates in
// place (all loads feed tau before any store issues => safe), duplicates
// into A, accumulates sparse PV, writes V row.
// ---------------------------------------------------------------------------
__device__ __forceinline__ void sparsemax_pv_row(size_t row, int lane,
                                                 float* __restrict__ G,
                                                 float* __restrict__ A,
                                                 const float* __restrict__ Val,
                                                 float* __restrict__ Vout) {
    const int b = (int)(row >> 11);                             // NN = 2048
    const short* z16 = (const short*)G + row * 4096;            // byte off row*8192
    float* grow = G + row * SS;
    float* arow = A + row * SS;
    const float* vb = Val + (size_t)b * SS * DD;

    // load int16 scores: 64 B/lane, coalesced, L2/L3-resident
    float v[32];
#pragma unroll
    for (int c = 0; c < 4; ++c) {
        s16x8 zz = *(const s16x8*)(z16 + c * 512 + lane * 8);
#pragma unroll
        for (int k = 0; k < 8; ++k) v[c * 8 + k] = (float)zz[k] * 0.00390625f;
    }

    // wave max
    float m = v[0];
#pragma unroll
    for (int j = 1; j < 32; ++j) m = fmaxf(m, v[j]);
#pragma unroll
    for (int off = 32; off > 0; off >>= 1) m = fmaxf(m, __shfl_xor(m, off, 64));

    // prune: per-lane top-4 candidates above m-1 (tau >= m-1 always)
    const float thr = m - 1.0f;
    float c0v = -1e30f, c1v = -1e30f, c2v = -1e30f, c3v = -1e30f;
    int nc = 0;
#pragma unroll
    for (int j = 0; j < 32; ++j) {
        float x = v[j];
        if (x > thr) { c3v = c2v; c2v = c1v; c1v = c0v; c0v = x; ++nc; }
    }

    float tau;
    if (__ballot(nc > 4) == 0ULL) {
        // fast path: bisect + Michelot over <=4 candidate regs
        float lo = thr, hi = m;
        for (int it = 0; it < 10; ++it) {
            float mid = 0.5f * (lo + hi);
            float p = fmaxf(c0v - mid, 0.f) + fmaxf(c1v - mid, 0.f)
                    + fmaxf(c2v - mid, 0.f) + fmaxf(c3v - mid, 0.f);
#pragma unroll
            for (int off = 32; off > 0; off >>= 1) p += __shfl_xor(p, off, 64);
            if (p >= 1.0f) lo = mid; else hi = mid;
        }
        tau = lo;
        for (int it = 0; it < 4; ++it) {
            float cnt = 0.f, s = 0.f;
            if (c0v > tau) { cnt += 1.f; s += c0v; }
            if (c1v > tau) { cnt += 1.f; s += c1v; }
            if (c2v > tau) { cnt += 1.f; s += c2v; }
            if (c3v > tau) { cnt += 1.f; s += c3v; }
#pragma unroll
            for (int off = 32; off > 0; off >>= 1) {
                cnt += __shfl_xor(cnt, off, 64);
                s   += __shfl_xor(s, off, 64);
            }
            tau = (s - 1.0f) / cnt;
        }
    } else {
        // cold fallback: full-register path (exact for any data)
        float lo = thr, hi = m;
        for (int it = 0; it < 10; ++it) {
            float mid = 0.5f * (lo + hi);
            float p = 0.f;
#pragma unroll
            for (int j = 0; j < 32; ++j) p += fmaxf(v[j] - mid, 0.f);
#pragma unroll
            for (int off = 32; off > 0; off >>= 1) p += __shfl_xor(p, off, 64);
            if (p >= 1.0f) lo = mid; else hi = mid;
        }
        tau = lo;
        for (int it = 0; it < 4; ++it) {
            float cnt = 0.f, s = 0.f;
#pragma unroll
            for (int j = 0; j < 32; ++j) {
                if (v[j] > tau) { cnt += 1.f; s += v[j]; }
            }
#pragma unroll
            for (int off = 32; off > 0; off >>= 1) {
                cnt += __shfl_xor(cnt, off, 64);
                s   += __shfl_xor(s, off, 64);
            }
            tau = (s - 1.0f) / cnt;
        }
    }

    // gates, dual nontemporal store (overwrites this row's own score bytes;
    // every v load precedes every store via the tau data dependency)
    float g[32];
#pragma unroll
    for (int c = 0; c < 4; ++c) {
#pragma unroll
        for (int k = 0; k < 8; ++k) g[c * 8 + k] = fmaxf(v[c * 8 + k] - tau, 0.f);
        float* gp = grow + c * 512 + lane * 8;
        float* ap = arow + c * 512 + lane * 8;
        nt_store4(gp,     g[c*8+0], g[c*8+1], g[c*8+2], g[c*8+3]);
        nt_store4(gp + 4, g[c*8+4], g[c*8+5], g[c*8+6], g[c*8+7]);
        nt_store4(ap,     g[c*8+0], g[c*8+1], g[c*8+2], g[c*8+3]);
        nt_store4(ap + 4, g[c*8+4], g[c*8+5], g[c*8+6], g[c*8+7]);
    }

    // sparse PV from registers (support is tiny: expected 1-3 columns)
    float4 acc = make_float4(0.f, 0.f, 0.f, 0.f);
#pragma unroll
    for (int c = 0; c < 4; ++c) {
#pragma unroll
        for (int k = 0; k < 8; ++k) {
            float a = g[c * 8 + k];
            unsigned long long mask = __ballot(a != 0.0f);
            while (mask) {
                int src = __builtin_ctzll(mask);
                mask &= mask - 1;
                float aa = __shfl(a, src, 64);
                int s = c * 512 + src * 8 + k;
                float4 vv = *(const float4*)(vb + (size_t)s * DD + lane * 4);
                acc.x += aa * vv.x;
                acc.y += aa * vv.y;
                acc.z += aa * vv.z;
                acc.w += aa * vv.w;
            }
        }
    }

    nt_store4(Vout + row * DD + lane * 4, acc.x, acc.y, acc.z, acc.w);
}

// ---------------------------------------------------------------------------
// FUSED kernel: each block owns 64 Q-rows end-to-end.
// Phase 1: s-loop over 8 K-passes of 64x256; per pass, d-loop 8 x BK=32 with
// double-buffered global_load_lds staging. 4 waves, each a 64x64 tile
// (acc[4][4], 12 ds_read_b128 : 32 MFMA — the proven k1 inner structure).
// Scores written int16 Q7.8 into the block's own G row-slots (L2-local).
// Phase 2: __syncthreads, then 4 waves x 16 rows of sparsemax_pv_row on the
// scores this block just produced. No cross-kernel boundary, no launch gap,
// no L3 round trip.
// ---------------------------------------------------------------------------
__global__ __launch_bounds__(256, 3) void k_fused(const _Float16* __restrict__ stash,
                                                  float* __restrict__ G,
                                                  float* __restrict__ A,
                                                  const float* __restrict__ Val,
                                                  float* __restrict__ Vout) {
    __shared__ _Float16 Qh[2][64 * 32];    // 8 KB
    __shared__ _Float16 Ql[2][64 * 32];    // 8 KB
    __shared__ _Float16 Kh[2][256 * 32];   // 32 KB  -> 48 KB total, 3 blocks/CU

    const _Float16* Qhi = stash;
    const _Float16* Qlo = stash + (size_t)EE;
    const _Float16* Khi = stash + 2 * (size_t)EE;

    const int t    = threadIdx.x;
    const int wave = t >> 6;
    const int lane = t & 63;
    const size_t r0 = (size_t)blockIdx.x * 64;   // global q-row base (64 | 2048)
    const int b = (int)(r0 >> 11);

    // staging: 16 B chunk per thread per array; LDS-linear (chunk = t*16 B)
    const int qrow = t >> 2;                     // 0..63
    const int qsd  = (t & 3) << 3;               // 0,8,16,24 elems
    const int qlds = qrow * 32 + qsd;
    const size_t qg = (r0 + (size_t)qrow) * DD + qsd;
    const size_t kb = (size_t)b * SS * DD;

    const int wx   = wave;                       // 0..3: 64-col strip of the K-pass
    const int frag = (lane & 15) * 32 + (lane >> 4) * 8;

    floatx4 acc[4][4] = {};
    short* G16 = (short*)G;

    // prologue: stage (s0=0, d0=0) into buffer 0
    async16(Qhi + qg, &Qh[0][qlds]);
    async16(Qlo + qg, &Ql[0][qlds]);
#pragma unroll
    for (int k = 0; k < 4; ++k)
        async16(Khi + kb + (size_t)(qrow + 64 * k) * DD + qsd,
                &Kh[0][(qrow + 64 * k) * 32 + qsd]);

    // flattened (s-pass, d-step) loop: it -> s0 = (it>>3)*256, d0 = (it&7)*32
    for (int it = 0; it < 64; ++it) {
        const int buf = it & 1;
        // drains this thread's outstanding global_load_lds (vmcnt 0) and
        // guarantees everyone is done reading the buffer we refill next.
        __syncthreads();

        if (it < 63) {
            const int nit = it + 1;
            const int ns0 = (nit >> 3) << 8;
            const int nd0 = (nit & 7) << 5;
            const int nb  = buf ^ 1;
            async16(Qhi + qg + nd0, &Qh[nb][qlds]);
            async16(Qlo + qg + nd0, &Ql[nb][qlds]);
#pragma unroll
            for (int k = 0; k < 4; ++k)
                async16(Khi + kb + (size_t)(ns0 + qrow + 64 * k) * DD + nd0 + qsd,
                        &Kh[nb][(qrow + 64 * k) * 32 + qsd]);
        }

        f16x8 qh[4], ql[4], kh[4];
#pragma unroll
        for (int i = 0; i < 4; ++i) {
            qh[i] = *(const f16x8*)&Qh[buf][(i * 16) * 32 + frag];
            ql[i] = *(const f16x8*)&Ql[buf][(i * 16) * 32 + frag];
            kh[i] = *(const f16x8*)&Kh[buf][(wx * 64 + i * 16) * 32 + frag];
        }
#pragma unroll
        for (int i = 0; i < 4; ++i)
#pragma unroll
            for (int j = 0; j < 4; ++j) {
                acc[i][j] = __builtin_amdgcn_mfma_f32_16x16x32_f16(qh[i], kh[j], acc[i][j], 0, 0, 0);
                acc[i][j] = __builtin_amdgcn_mfma_f32_16x16x32_f16(ql[i], kh[j], acc[i][j], 0, 0, 0);
            }

        // end of a 256-col K-pass: emit int16 scores, reset acc
        if ((it & 7) == 7) {
            const int s0 = (it >> 3) << 8;
            const size_t rr0 = r0 + (lane >> 4) * 4;   // C/D: col=lane&15, row=(lane>>4)*4+reg
            const int c0 = s0 + wx * 64 + (lane & 15);
#pragma unroll
            for (int i = 0; i < 4; ++i)
#pragma unroll
                for (int j = 0; j < 4; ++j) {
#pragma unroll
                    for (int r = 0; r < 4; ++r) {
                        float x = acc[i][j][r] * 256.0f;
                        x = fminf(fmaxf(x, -32767.0f), 32767.0f);
                        G16[(rr0 + i * 16 + r) * 4096 + c0 + j * 16] = (short)__float2int_rn(x);
                    }
                    acc[i][j] = (floatx4){0.f, 0.f, 0.f, 0.f};
                }
        }
    }

    // phase boundary: all score stores retired (barrier drains vmcnt),
    // cross-wave visibility via same-CU L2 (no stale L1: G never read before)
    __syncthreads();

#pragma unroll 1
    for (int rr = 0; rr < 16; ++rr)
        sparsemax_pv_row(r0 + (size_t)wave * 16 + rr, lane, G, A, Val, Vout);
}

// ---------------------------------------------------------------------------
// Fallback kernels (proven R2 path) — used only if ws_size < STASH_BYTES.
// ---------------------------------------------------------------------------
__global__ __launch_bounds__(256) void k_scores_mfma(const _Float16* __restrict__ stash,
                                                     float* __restrict__ out) {
    __shared__ _Float16 Qh[2][128 * 32];
    __shared__ _Float16 Ql[2][128 * 32];
    __shared__ _Float16 Kh[2][128 * 32];

    const _Float16* Qhi = stash;
    const _Float16* Qlo = stash + (size_t)EE;
    const _Float16* Khi = stash + 2 * (size_t)EE;

    const int b  = blockIdx.z;
    const int n0 = blockIdx.y * 128;
    const int s0 = blockIdx.x * 128;

    const int t    = threadIdx.x;
    const int wave = t >> 6;
    const int lane = t & 63;

    const int srow = (wave << 4) + (lane >> 2);
    const int sd   = (lane & 3) << 3;
    const int lds0 = srow * 32 + sd;
    const size_t qg = (size_t)b * NN * DD + (size_t)(n0 + srow) * DD + sd;
    const size_t kg = (size_t)b * SS * DD + (size_t)(s0 + srow) * DD + sd;

    const int wy = wave >> 1, wx = wave & 1;
    const int frag = (lane & 15) * 32 + (lane >> 4) * 8;

    floatx4 acc[4][4] = {};

    async16(Qhi + qg,           &Qh[0][lds0]);
    async16(Qhi + qg + 64 * DD, &Qh[0][lds0 + 2048]);
    async16(Qlo + qg,           &Ql[0][lds0]);
    async16(Qlo + qg + 64 * DD, &Ql[0][lds0 + 2048]);
    async16(Khi + kg,           &Kh[0][lds0]);
    async16(Khi + kg + 64 * DD, &Kh[0][lds0 + 2048]);

    for (int it = 0; it < 8; ++it) {
        const int cur = it & 1;
        __syncthreads();

        if (it < 7) {
            const int nxt = cur ^ 1;
            const int d1 = (it + 1) * 32;
            async16(Qhi + qg + d1,           &Qh[nxt][lds0]);
            async16(Qhi + qg + d1 + 64 * DD, &Qh[nxt][lds0 + 2048]);
            async16(Qlo + qg + d1,           &Ql[nxt][lds0]);
            async16(Qlo + qg + d1 + 64 * DD, &Ql[nxt][lds0 + 2048]);
            async16(Khi + kg + d1,           &Kh[nxt][lds0]);
            async16(Khi + kg + d1 + 64 * DD, &Kh[nxt][lds0 + 2048]);
        }

        f16x8 qh[4], ql[4], kh[4];
#pragma unroll
        for (int i = 0; i < 4; ++i) {
            qh[i] = *(const f16x8*)&Qh[cur][(wy * 64 + i * 16) * 32 + frag];
            ql[i] = *(const f16x8*)&Ql[cur][(wy * 64 + i * 16) * 32 + frag];
            kh[i] = *(const f16x8*)&Kh[cur][(wx * 64 + i * 16) * 32 + frag];
        }
#pragma unroll
        for (int i = 0; i < 4; ++i)
#pragma unroll
            for (int j = 0; j < 4; ++j) {
                acc[i][j] = __builtin_amdgcn_mfma_f32_16x16x32_f16(qh[i], kh[j], acc[i][j], 0, 0, 0);
                acc[i][j] = __builtin_amdgcn_mfma_f32_16x16x32_f16(ql[i], kh[j], acc[i][j], 0, 0, 0);
            }
    }

    short* G16 = (short*)out;
    const size_t r0 = (size_t)b * NN + n0 + wy * 64 + (lane >> 4) * 4;
    const int    c0 = s0 + wx * 64 + (lane & 15);
#pragma unroll
    for (int i = 0; i < 4; ++i)
#pragma unroll
        for (int j = 0; j < 4; ++j)
#pragma unroll
            for (int r = 0; r < 4; ++r) {
                float x = acc[i][j][r] * 256.0f;
                x = fminf(fmaxf(x, -32767.0f), 32767.0f);
                G16[(r0 + i * 16 + r) * 4096 + c0 + j * 16] = (short)__float2int_rn(x);
            }
}

__global__ __launch_bounds__(256) void k_sparsemax_pv(float* __restrict__ G,
                                                      float* __restrict__ A,
                                                      const float* __restrict__ Val,
                                                      float* __restrict__ Vout) {
    const int t = threadIdx.x;
    const int lane = t & 63;
    const size_t rblk = (size_t)(gridDim.x - 1 - blockIdx.x);   // reversed
    const size_t row = rblk * 4 + (t >> 6);
    sparsemax_pv_row(row, lane, G, A, Val, Vout);
}

extern "C" void kernel_launch(void* const* d_in, const int* in_sizes, int n_in,
                              void* d_out, int out_size, void* d_ws, size_t ws_size,
                              hipStream_t stream) {
    const float* Q = (const float*)d_in[0];
    const float* K = (const float*)d_in[1];
    const float* V = (const float*)d_in[2];

    float* out  = (float*)d_out;
    float* Vout = out;                                   // [B,N,D]
    float* Aout = out + (size_t)BB * NN * DD;            // [B,N,S]
    float* Gout = Aout + (size_t)BB * NN * SS;           // [B,N,S]

    if (ws_size >= STASH_BYTES) {
        // fused path: stash in workspace (A region would race with phase-2)
        _Float16* stash = (_Float16*)d_ws;
        hipLaunchKernelGGL(k_convert, dim3((2 * EE / 4) / 256), dim3(256), 0, stream,
                           Q, K, stash);
        hipLaunchKernelGGL(k_fused, dim3((BB * NN) / 64), dim3(256), 0, stream,
                           stash, Gout, Aout, V, Vout);
    } else {
        // fallback: proven R2 three-kernel path, stash in A region
        _Float16* stash = (_Float16*)Aout;
        hipLaunchKernelGGL(k_convert, dim3((2 * EE / 4) / 256), dim3(256), 0, stream,
                           Q, K, stash);
        dim3 g1(SS / 128, NN / 128, BB);
        hipLaunchKernelGGL(k_scores_mfma, g1, dim3(256), 0, stream, stash, Gout);
        hipLaunchKernelGGL(k_sparsemax_pv, dim3((BB * NN) / 4), dim3(256), 0, stream,
                           Gout, Aout, V, Vout);
    }
}

// Round 4
// 706.005 us; speedup vs baseline: 1.1077x; 1.1077x over previous
//
#include <hip/hip_runtime.h>
#include <hip/hip_bf16.h>

// Problem constants (B=16, N=S=2048, D=256, fp32 in/out).
#define BB 16
#define NN 2048
#define SS 2048
#define DD 256
#define EE (BB * NN * DD)  // 8388608 elements per tensor

typedef _Float16 f16x8 __attribute__((ext_vector_type(8)));
typedef _Float16 f16x4 __attribute__((ext_vector_type(4)));
typedef float floatx4 __attribute__((ext_vector_type(4)));
typedef short s16x8 __attribute__((ext_vector_type(8)));

__device__ __forceinline__ void async16(const _Float16* g, _Float16* l) {
    __builtin_amdgcn_global_load_lds((__attribute__((address_space(1))) void*)g,
                                     (__attribute__((address_space(3))) void*)l, 16, 0, 0);
}

__device__ __forceinline__ void nt_store4(float* p, float x, float y, float z, float w) {
    floatx4 v = {x, y, z, w};
    __builtin_nontemporal_store(v, (floatx4*)p);
}

// ---------------------------------------------------------------------------
// Kernel 0: fp16 convert. Q -> Qh, K -> Kh (round-to-nearest). 1-term score
// error model: z_err = sum(ql*kh) + sum(q*kl) — two independent fp16-rounding
// terms; measured 2-term absmax was 0.0508 (K term only), so 1-term ~ x sqrt2
// ~ 0.072 < 0.104 threshold. stash (fp16): Qh[EE] | Kh[EE] = 33.5 MB in the
// A-output region (consumed by k1 before k2 writes A — stream-serialized).
// ---------------------------------------------------------------------------
__global__ __launch_bounds__(256) void k_convert(const float* __restrict__ Q,
                                                 const float* __restrict__ K,
                                                 _Float16* __restrict__ stash) {
    size_t idx = ((size_t)blockIdx.x * 256 + threadIdx.x) * 4;  // over 2*EE elems
    const float* src = (idx < (size_t)EE) ? (Q + idx) : (K + (idx - (size_t)EE));
    float4 v = *(const float4*)src;
    f16x4 h;
    h.x = (_Float16)v.x; h.y = (_Float16)v.y; h.z = (_Float16)v.z; h.w = (_Float16)v.w;
    *(f16x4*)(stash + idx) = h;
}

// ---------------------------------------------------------------------------
// Kernel 1: scores = Qh @ Kh^T via 1-term fp16 MFMA.
// 128x128 tile / block, 4 waves each 64x64 (4x4 tiles of 16x16x32_f16).
// Double-buffered global_load_lds staging (LDS 32 KB -> 5 blocks/CU).
// C written as int16 Q7.8 (round(z*256), abs err <= 1/512) into the FIRST
// HALF of each row's fp32 G slot (row r at byte r*8192) — 67 MB interchange,
// L2/L3-resident for kernel 2, self-owned per row.
// ---------------------------------------------------------------------------
__global__ __launch_bounds__(256) void k_scores_mfma(const _Float16* __restrict__ stash,
                                                     float* __restrict__ out) {
    __shared__ _Float16 Qh[2][128 * 32];
    __shared__ _Float16 Kh[2][128 * 32];

    const _Float16* Qhi = stash;
    const _Float16* Khi = stash + (size_t)EE;

    const int b  = blockIdx.z;
    const int n0 = blockIdx.y * 128;
    const int s0 = blockIdx.x * 128;

    const int t    = threadIdx.x;
    const int wave = t >> 6;
    const int lane = t & 63;

    // staging: row within 64-row pass, 16B d-chunk
    const int srow = (wave << 4) + (lane >> 2);   // 0..63
    const int sd   = (lane & 3) << 3;             // 0,8,16,24 elems
    const int lds0 = srow * 32 + sd;
    const size_t qg = (size_t)b * NN * DD + (size_t)(n0 + srow) * DD + sd;
    const size_t kg = (size_t)b * SS * DD + (size_t)(s0 + srow) * DD + sd;

    // fragment read offsets
    const int wy = wave >> 1, wx = wave & 1;
    const int frag = (lane & 15) * 32 + (lane >> 4) * 8;

    floatx4 acc[4][4] = {};

    // prologue: stage d0 = 0 into buffer 0
    async16(Qhi + qg,           &Qh[0][lds0]);
    async16(Qhi + qg + 64 * DD, &Qh[0][lds0 + 2048]);
    async16(Khi + kg,           &Kh[0][lds0]);
    async16(Khi + kg + 64 * DD, &Kh[0][lds0 + 2048]);

    for (int it = 0; it < 8; ++it) {
        const int cur = it & 1;
        // drains this thread's outstanding global_load_lds (vmcnt 0) and
        // guarantees everyone is done READING the buffer we refill next.
        __syncthreads();

        if (it < 7) {
            const int nxt = cur ^ 1;
            const int d1 = (it + 1) * 32;
            async16(Qhi + qg + d1,           &Qh[nxt][lds0]);
            async16(Qhi + qg + d1 + 64 * DD, &Qh[nxt][lds0 + 2048]);
            async16(Khi + kg + d1,           &Kh[nxt][lds0]);
            async16(Khi + kg + d1 + 64 * DD, &Kh[nxt][lds0 + 2048]);
        }

        f16x8 qh[4], kh[4];
#pragma unroll
        for (int i = 0; i < 4; ++i) {
            qh[i] = *(const f16x8*)&Qh[cur][(wy * 64 + i * 16) * 32 + frag];
            kh[i] = *(const f16x8*)&Kh[cur][(wx * 64 + i * 16) * 32 + frag];
        }
#pragma unroll
        for (int i = 0; i < 4; ++i)
#pragma unroll
            for (int j = 0; j < 4; ++j)
                acc[i][j] = __builtin_amdgcn_mfma_f32_16x16x32_f16(qh[i], kh[j], acc[i][j], 0, 0, 0);
    }

    // C/D layout: col = lane&15, row = (lane>>4)*4 + reg.
    // int16 Q7.8 store into row slot: elem index (b*NN + n) * 4096 + s.
    short* G16 = (short*)out;
    const size_t r0 = (size_t)b * NN + n0 + wy * 64 + (lane >> 4) * 4;
    const int    c0 = s0 + wx * 64 + (lane & 15);
#pragma unroll
    for (int i = 0; i < 4; ++i)
#pragma unroll
        for (int j = 0; j < 4; ++j)
#pragma unroll
            for (int r = 0; r < 4; ++r) {
                float x = acc[i][j][r] * 256.0f;
                x = fminf(fmaxf(x, -32767.0f), 32767.0f);
                G16[(r0 + i * 16 + r) * 4096 + c0 + j * 16] = (short)__float2int_rn(x);
            }
}

// ---------------------------------------------------------------------------
// Kernel 2 (fused): row-wise sparsemax + sparse PV (proven R2 logic).
// One wave per row, reversed block order (harvest L3-newest scores first).
// Reads the int16 Q7.8 score half-slot of its own row, expands to fp32 gates
// in place; tau via pruned top-4 candidates (tau >= m-1 always) with exact
// full-register fallback.
// ---------------------------------------------------------------------------
__global__ __launch_bounds__(256) void k_sparsemax_pv(float* __restrict__ G,
                                                      float* __restrict__ A,
                                                      const float* __restrict__ Val,
                                                      float* __restrict__ Vout) {
    const int t = threadIdx.x;
    const int lane = t & 63;
    const size_t rblk = (size_t)(gridDim.x - 1 - blockIdx.x);   // reversed
    const size_t row = rblk * 4 + (t >> 6);                     // over B*N
    const int b = (int)(row >> 11);                             // NN = 2048
    const short* z16 = (const short*)G + row * 4096;            // byte off row*8192
    float* grow = G + row * SS;
    float* arow = A + row * SS;
    const float* vb = Val + (size_t)b * SS * DD;

    // load int16 scores: 64 B/lane, coalesced, L2/L3-resident
    float v[32];
#pragma unroll
    for (int c = 0; c < 4; ++c) {
        s16x8 zz = *(const s16x8*)(z16 + c * 512 + lane * 8);
#pragma unroll
        for (int k = 0; k < 8; ++k) v[c * 8 + k] = (float)zz[k] * 0.00390625f;
    }

    // wave max
    float m = v[0];
#pragma unroll
    for (int j = 1; j < 32; ++j) m = fmaxf(m, v[j]);
#pragma unroll
    for (int off = 32; off > 0; off >>= 1) m = fmaxf(m, __shfl_xor(m, off, 64));

    // prune: per-lane top-4 candidates above m-1 (tau >= m-1 always)
    const float thr = m - 1.0f;
    float c0v = -1e30f, c1v = -1e30f, c2v = -1e30f, c3v = -1e30f;
    int nc = 0;
#pragma unroll
    for (int j = 0; j < 32; ++j) {
        float x = v[j];
        if (x > thr) { c3v = c2v; c2v = c1v; c1v = c0v; c0v = x; ++nc; }
    }

    float tau;
    if (__ballot(nc > 4) == 0ULL) {
        // fast path: bisect + Michelot over <=4 candidate regs
        float lo = thr, hi = m;
        for (int it = 0; it < 10; ++it) {
            float mid = 0.5f * (lo + hi);
            float p = fmaxf(c0v - mid, 0.f) + fmaxf(c1v - mid, 0.f)
                    + fmaxf(c2v - mid, 0.f) + fmaxf(c3v - mid, 0.f);
#pragma unroll
            for (int off = 32; off > 0; off >>= 1) p += __shfl_xor(p, off, 64);
            if (p >= 1.0f) lo = mid; else hi = mid;
        }
        tau = lo;
        for (int it = 0; it < 4; ++it) {
            float cnt = 0.f, s = 0.f;
            if (c0v > tau) { cnt += 1.f; s += c0v; }
            if (c1v > tau) { cnt += 1.f; s += c1v; }
            if (c2v > tau) { cnt += 1.f; s += c2v; }
            if (c3v > tau) { cnt += 1.f; s += c3v; }
#pragma unroll
            for (int off = 32; off > 0; off >>= 1) {
                cnt += __shfl_xor(cnt, off, 64);
                s   += __shfl_xor(s, off, 64);
            }
            tau = (s - 1.0f) / cnt;
        }
    } else {
        // cold fallback: full-register path (exact for any data)
        float lo = thr, hi = m;
        for (int it = 0; it < 10; ++it) {
            float mid = 0.5f * (lo + hi);
            float p = 0.f;
#pragma unroll
            for (int j = 0; j < 32; ++j) p += fmaxf(v[j] - mid, 0.f);
#pragma unroll
            for (int off = 32; off > 0; off >>= 1) p += __shfl_xor(p, off, 64);
            if (p >= 1.0f) lo = mid; else hi = mid;
        }
        tau = lo;
        for (int it = 0; it < 4; ++it) {
            float cnt = 0.f, s = 0.f;
#pragma unroll
            for (int j = 0; j < 32; ++j) {
                if (v[j] > tau) { cnt += 1.f; s += v[j]; }
            }
#pragma unroll
            for (int off = 32; off > 0; off >>= 1) {
                cnt += __shfl_xor(cnt, off, 64);
                s   += __shfl_xor(s, off, 64);
            }
            tau = (s - 1.0f) / cnt;
        }
    }

    // gates, dual nontemporal store (overwrites this row's own score bytes;
    // every v load precedes every store via the tau data dependency)
    float g[32];
#pragma unroll
    for (int c = 0; c < 4; ++c) {
#pragma unroll
        for (int k = 0; k < 8; ++k) g[c * 8 + k] = fmaxf(v[c * 8 + k] - tau, 0.f);
        float* gp = grow + c * 512 + lane * 8;
        float* ap = arow + c * 512 + lane * 8;
        nt_store4(gp,     g[c*8+0], g[c*8+1], g[c*8+2], g[c*8+3]);
        nt_store4(gp + 4, g[c*8+4], g[c*8+5], g[c*8+6], g[c*8+7]);
        nt_store4(ap,     g[c*8+0], g[c*8+1], g[c*8+2], g[c*8+3]);
        nt_store4(ap + 4, g[c*8+4], g[c*8+5], g[c*8+6], g[c*8+7]);
    }

    // sparse PV from registers (support is tiny: expected 1-3 columns)
    float4 acc = make_float4(0.f, 0.f, 0.f, 0.f);
#pragma unroll
    for (int c = 0; c < 4; ++c) {
#pragma unroll
        for (int k = 0; k < 8; ++k) {
            float a = g[c * 8 + k];
            unsigned long long mask = __ballot(a != 0.0f);
            while (mask) {
                int src = __builtin_ctzll(mask);
                mask &= mask - 1;
                float aa = __shfl(a, src, 64);
                int s = c * 512 + src * 8 + k;
                float4 vv = *(const float4*)(vb + (size_t)s * DD + lane * 4);
                acc.x += aa * vv.x;
                acc.y += aa * vv.y;
                acc.z += aa * vv.z;
                acc.w += aa * vv.w;
            }
        }
    }

    nt_store4(Vout + row * DD + lane * 4, acc.x, acc.y, acc.z, acc.w);
}

extern "C" void kernel_launch(void* const* d_in, const int* in_sizes, int n_in,
                              void* d_out, int out_size, void* d_ws, size_t ws_size,
                              hipStream_t stream) {
    const float* Q = (const float*)d_in[0];
    const float* K = (const float*)d_in[1];
    const float* V = (const float*)d_in[2];

    float* out  = (float*)d_out;
    float* Vout = out;                                   // [B,N,D]
    float* Aout = out + (size_t)BB * NN * DD;            // [B,N,S]
    float* Gout = Aout + (size_t)BB * NN * SS;           // [B,N,S]

    // 0) fp16 convert: Qh|Kh stash (lives in Aout region until k2 writes A)
    _Float16* stash = (_Float16*)Aout;
    hipLaunchKernelGGL(k_convert, dim3((2 * EE / 4) / 256), dim3(256), 0, stream,
                       Q, K, stash);

    // 1) scores -> int16 Q7.8 half-slots in the G region (row r at byte r*8192)
    dim3 g1(SS / 128, NN / 128, BB);
    hipLaunchKernelGGL(k_scores_mfma, g1, dim3(256), 0, stream, stash, Gout);

    // 2) fused sparsemax + PV: int16 scores -> fp32 gates in place, duplicate
    //    into A, V out
    hipLaunchKernelGGL(k_sparsemax_pv, dim3((BB * NN) / 4), dim3(256), 0, stream,
                       Gout, Aout, V, Vout);
}